// Round 2
// baseline (224.524 us; speedup 1.0000x reference)
//
#include <hip/hip_runtime.h>

// ---------- kernel 1: bucket tokens by partition ----------
__global__ void bucket_k(const int* __restrict__ x, const int* __restrict__ parts,
                         int* __restrict__ counts, int* __restrict__ buckets, int NT) {
    int i = blockIdx.x * blockDim.x + threadIdx.x;
    if (i >= NT) return;
    int tok = x[i];
    int p = parts[tok];
    int pos = atomicAdd(&counts[p], 1);
    buckets[(size_t)p * NT + pos] = i;
}

// ---------- kernel 2: grouped GEMM per partition (fp32) ----------
// Specialized: D=256, P=8. Block = 256 threads. Grid (XB, 4 z-tiles, 8 partitions).
// W slab [64 z][K<=256 x] staged to LDS ONCE per block (x-major), then block loops
// 64-token tiles of its partition, chunking E by KC=32.
// Per lane: 4 tokens x 4 z fp32 accumulators; inner step = 2 ds_read_b128 + 16 FMA.
#define KC 32
#define XB 32

__global__ __launch_bounds__(256)
void fge_gemm(const int* __restrict__ x,
              const float* __restrict__ emb,
              const float* __restrict__ weight,
              const int* __restrict__ counts,
              const int* __restrict__ buckets,
              float* __restrict__ out, int NT) {
    const int p = blockIdx.z;
    const int n = counts[p];
    if ((int)(blockIdx.x * 64) >= n) return;        // block-uniform early exit
    const int z0  = blockIdx.y * 64;
    const int K   = 256 >> p;                       // active input dim
    const int tid = threadIdx.x;

    __shared__ __align__(16) float w_lds[256][64];  // [x][z]  64 KB
    __shared__ __align__(16) float e_lds[KC][64];   // [x][tok] 8 KB
    __shared__ int vrow[64];
    __shared__ int oidx[64];

    // ---- stage W slab once (x-major transpose; zero-pad x in [K, 32) for small K) ----
    {
        const int Kpad = (K < KC) ? KC : K;         // compute only ever reads x < max(K,32)
        const int wrow = tid >> 2;                  // z row 0..63
        const float* wbase = weight + ((size_t)p * 256 + (z0 + wrow)) * 256;
        for (int colb = (tid & 3) * 4; colb < Kpad; colb += 16) {
            float4 v = *(const float4*)(wbase + colb);   // 64B-coalesced per 4 lanes
            float vv[4] = {v.x, v.y, v.z, v.w};
#pragma unroll
            for (int c = 0; c < 4; ++c)
                w_lds[colb + c][wrow] = (colb + c < K) ? vv[c] : 0.f;
        }
    }

    const int tz  = tid & 15;     // z-group: owns z0 + tz*4 .. +3  (coalesced stores)
    const int tt  = tid >> 4;     // token-group: owns tokens tt*4 .. +3
    const int t_l = tid & 63;     // staging: token slot
    const int xh  = tid >> 6;     // staging: x sub-range xh*8 .. +7
    const int nch = (K + KC - 1) / KC;

    for (int t0 = blockIdx.x * 64; t0 < n; t0 += XB * 64) {
        const int ntile = min(64, n - t0);

        __syncthreads();          // W slab visible (iter 0); oidx safe to overwrite (iter >0)
        if (tid < 64) {
            int idx = 0, row = 0;
            if (t_l < ntile) {
                idx = buckets[(size_t)p * NT + t0 + t_l];
                row = x[idx];
            }
            oidx[t_l] = idx;
            vrow[t_l] = row;
        }
        __syncthreads();          // vrow visible to all stagers

        float acc[4][4] = {};

        for (int ch = 0; ch < nch; ++ch) {
            // ---- stage E chunk (zero-fill beyond K / beyond ntile) ----
            {
                const bool tv = (t_l < ntile);
                const float* er = emb + (size_t)vrow[t_l] * 256;
                const int gxb = ch * KC + xh * 8;
                float4 a = *(const float4*)(er + gxb);       // always in-bounds
                float4 b = *(const float4*)(er + gxb + 4);
                float va[8] = {a.x, a.y, a.z, a.w, b.x, b.y, b.z, b.w};
#pragma unroll
                for (int c = 0; c < 8; ++c) {
                    int gx = gxb + c;
                    e_lds[xh * 8 + c][t_l] = (tv && gx < K) ? va[c] : 0.f;
                }
            }
            __syncthreads();

            // ---- compute: 32 x-steps, 2 ds_read_b128 + 16 FMA each ----
#pragma unroll
            for (int c = 0; c < KC; ++c) {
                const float4 ev = *(const float4*)&e_lds[c][tt * 4];
                const float4 wv = *(const float4*)&w_lds[ch * KC + c][tz * 4];
                const float ea[4] = {ev.x, ev.y, ev.z, ev.w};
                const float wa[4] = {wv.x, wv.y, wv.z, wv.w};
#pragma unroll
                for (int i = 0; i < 4; ++i)
#pragma unroll
                    for (int j = 0; j < 4; ++j)
                        acc[i][j] = fmaf(ea[i], wa[j], acc[i][j]);
            }
            __syncthreads();      // before next chunk overwrites e_lds
        }

        // ---- epilogue: float4 stores, 16 lanes cover one token row's 64 z ----
#pragma unroll
        for (int i = 0; i < 4; ++i) {
            const int t = tt * 4 + i;
            if (t < ntile) {
                float4 o = {acc[i][0], acc[i][1], acc[i][2], acc[i][3]};
                *(float4*)(out + (size_t)oidx[t] * 256 + z0 + tz * 4) = o;
            }
        }
    }
}

// ---------- generic fallback (any D/P, or ws too small) ----------
__global__ void naive_k(const int* __restrict__ x, const float* __restrict__ emb,
                        const float* __restrict__ w, const int* __restrict__ parts,
                        float* __restrict__ out, int D, int P) {
    const int i = blockIdx.x;
    const int tokrow = x[i];
    const int p = parts[tokrow];
    const int K = D >> p;
    const float* er = emb + (size_t)tokrow * D;
    for (int z = threadIdx.x; z < D; z += blockDim.x) {
        const float* wr = w + ((size_t)p * D + z) * D;
        float acc = 0.f;
        for (int k = 0; k < K; ++k) acc = fmaf(er[k], wr[k], acc);
        out[(size_t)i * D + z] = acc;
    }
}

extern "C" void kernel_launch(void* const* d_in, const int* in_sizes, int n_in,
                              void* d_out, int out_size, void* d_ws, size_t ws_size,
                              hipStream_t stream) {
    const int*   xi    = (const int*)d_in[0];
    const float* emb   = (const float*)d_in[1];
    const float* wgt   = (const float*)d_in[2];
    const int*   parts = (const int*)d_in[3];
    float* out = (float*)d_out;

    const int NT = in_sizes[0];
    const long long V = in_sizes[3];
    const int D = (int)(in_sizes[1] / V);
    const int P = (int)(in_sizes[2] / ((long long)D * D));
    const size_t need = 32 + (size_t)P * (size_t)NT * sizeof(int);

    if (D == 256 && P == 8 && ws_size >= need) {
        int* counts  = (int*)d_ws;
        int* buckets = (int*)((char*)d_ws + 32);
        hipMemsetAsync(counts, 0, 32, stream);
        bucket_k<<<(NT + 255) / 256, 256, 0, stream>>>(xi, parts, counts, buckets, NT);
        dim3 grid(XB, 4, 8);
        fge_gemm<<<grid, 256, 0, stream>>>(xi, emb, wgt, counts, buckets, out, NT);
    } else {
        naive_k<<<NT, 256, 0, stream>>>(xi, emb, wgt, parts, out, D, P);
    }
}

// Round 3
// 164.016 us; speedup vs baseline: 1.3689x; 1.3689x over previous
//
#include <hip/hip_runtime.h>

// ---------- kernel 1: bucket tokens by partition ----------
// Two-phase block-aggregated atomics: 16384 same-line global atomics (64 us of
// L2-line serialization in R1) -> 8 LDS-aggregated global atomics per block.
__global__ void bucket_k(const int* __restrict__ x, const int* __restrict__ parts,
                         int* __restrict__ counts, int* __restrict__ buckets, int NT) {
    __shared__ int lcount[8];
    __shared__ int lbase[8];
    const int tid = threadIdx.x;
    if (tid < 8) lcount[tid] = 0;
    __syncthreads();

    const int i = blockIdx.x * blockDim.x + tid;
    int p = 0, lpos = 0;
    const bool valid = (i < NT);
    if (valid) {
        p = parts[x[i]];
        lpos = atomicAdd(&lcount[p], 1);        // LDS atomic: cheap
    }
    __syncthreads();
    if (tid < 8)
        lbase[tid] = lcount[tid] ? atomicAdd(&counts[tid], lcount[tid]) : 0;
    __syncthreads();
    if (valid)
        buckets[(size_t)p * NT + lbase[p] + lpos] = i;
}

// ---------- kernel 2: grouped GEMM per partition (fp32) ----------
// Specialized: D=256, P=8. Block = 256 threads. Grid (XB, 4 z-tiles, 8 partitions).
// W slab [64 z][K<=256 x] staged to LDS ONCE per block (x-major), then block loops
// 64-token tiles of its partition, chunking E by KC=32.
// Per lane: 4 tokens x 4 z fp32 accumulators; inner step = 2 ds_read_b128 + 16 FMA.
#define KC 32
#define XB 32

__global__ __launch_bounds__(256)
void fge_gemm(const int* __restrict__ x,
              const float* __restrict__ emb,
              const float* __restrict__ weight,
              const int* __restrict__ counts,
              const int* __restrict__ buckets,
              float* __restrict__ out, int NT) {
    const int p = blockIdx.z;
    const int n = counts[p];
    if ((int)(blockIdx.x * 64) >= n) return;        // block-uniform early exit
    const int z0  = blockIdx.y * 64;
    const int K   = 256 >> p;                       // active input dim
    const int tid = threadIdx.x;

    __shared__ __align__(16) float w_lds[256][64];  // [x][z]  64 KB
    __shared__ __align__(16) float e_lds[KC][64];   // [x][tok] 8 KB
    __shared__ int vrow[64];
    __shared__ int oidx[64];

    // ---- stage W slab once (x-major transpose; zero-pad x in [K, 32) for small K) ----
    {
        const int Kpad = (K < KC) ? KC : K;         // compute only ever reads x < max(K,32)
        const int wrow = tid >> 2;                  // z row 0..63
        const float* wbase = weight + ((size_t)p * 256 + (z0 + wrow)) * 256;
        for (int colb = (tid & 3) * 4; colb < Kpad; colb += 16) {
            float4 v = *(const float4*)(wbase + colb);   // 64B-coalesced per 4 lanes
            float vv[4] = {v.x, v.y, v.z, v.w};
#pragma unroll
            for (int c = 0; c < 4; ++c)
                w_lds[colb + c][wrow] = (colb + c < K) ? vv[c] : 0.f;
        }
    }

    const int tz  = tid & 15;     // z-group: owns z0 + tz*4 .. +3  (coalesced stores)
    const int tt  = tid >> 4;     // token-group: owns tokens tt*4 .. +3
    const int t_l = tid & 63;     // staging: token slot
    const int xh  = tid >> 6;     // staging: x sub-range xh*8 .. +7
    const int nch = (K + KC - 1) / KC;

    for (int t0 = blockIdx.x * 64; t0 < n; t0 += XB * 64) {
        const int ntile = min(64, n - t0);

        __syncthreads();          // W slab visible (iter 0); oidx safe to overwrite (iter >0)
        if (tid < 64) {
            int idx = 0, row = 0;
            if (t_l < ntile) {
                idx = buckets[(size_t)p * NT + t0 + t_l];
                row = x[idx];
            }
            oidx[t_l] = idx;
            vrow[t_l] = row;
        }
        __syncthreads();          // vrow visible to all stagers

        float acc[4][4] = {};

        for (int ch = 0; ch < nch; ++ch) {
            // ---- stage E chunk (zero-fill beyond K / beyond ntile) ----
            {
                const bool tv = (t_l < ntile);
                const float* er = emb + (size_t)vrow[t_l] * 256;
                const int gxb = ch * KC + xh * 8;
                float4 a = *(const float4*)(er + gxb);       // always in-bounds
                float4 b = *(const float4*)(er + gxb + 4);
                float va[8] = {a.x, a.y, a.z, a.w, b.x, b.y, b.z, b.w};
#pragma unroll
                for (int c = 0; c < 8; ++c) {
                    int gx = gxb + c;
                    e_lds[xh * 8 + c][t_l] = (tv && gx < K) ? va[c] : 0.f;
                }
            }
            __syncthreads();

            // ---- compute: 32 x-steps, 2 ds_read_b128 + 16 FMA each ----
#pragma unroll
            for (int c = 0; c < KC; ++c) {
                const float4 ev = *(const float4*)&e_lds[c][tt * 4];
                const float4 wv = *(const float4*)&w_lds[ch * KC + c][tz * 4];
                const float ea[4] = {ev.x, ev.y, ev.z, ev.w};
                const float wa[4] = {wv.x, wv.y, wv.z, wv.w};
#pragma unroll
                for (int i = 0; i < 4; ++i)
#pragma unroll
                    for (int j = 0; j < 4; ++j)
                        acc[i][j] = fmaf(ea[i], wa[j], acc[i][j]);
            }
            __syncthreads();      // before next chunk overwrites e_lds
        }

        // ---- epilogue: float4 stores, 16 lanes cover one token row's 64 z ----
#pragma unroll
        for (int i = 0; i < 4; ++i) {
            const int t = tt * 4 + i;
            if (t < ntile) {
                float4 o = {acc[i][0], acc[i][1], acc[i][2], acc[i][3]};
                *(float4*)(out + (size_t)oidx[t] * 256 + z0 + tz * 4) = o;
            }
        }
    }
}

// ---------- generic fallback (any D/P, or ws too small) ----------
__global__ void naive_k(const int* __restrict__ x, const float* __restrict__ emb,
                        const float* __restrict__ w, const int* __restrict__ parts,
                        float* __restrict__ out, int D, int P) {
    const int i = blockIdx.x;
    const int tokrow = x[i];
    const int p = parts[tokrow];
    const int K = D >> p;
    const float* er = emb + (size_t)tokrow * D;
    for (int z = threadIdx.x; z < D; z += blockDim.x) {
        const float* wr = w + ((size_t)p * D + z) * D;
        float acc = 0.f;
        for (int k = 0; k < K; ++k) acc = fmaf(er[k], wr[k], acc);
        out[(size_t)i * D + z] = acc;
    }
}

extern "C" void kernel_launch(void* const* d_in, const int* in_sizes, int n_in,
                              void* d_out, int out_size, void* d_ws, size_t ws_size,
                              hipStream_t stream) {
    const int*   xi    = (const int*)d_in[0];
    const float* emb   = (const float*)d_in[1];
    const float* wgt   = (const float*)d_in[2];
    const int*   parts = (const int*)d_in[3];
    float* out = (float*)d_out;

    const int NT = in_sizes[0];
    const long long V = in_sizes[3];
    const int D = (int)(in_sizes[1] / V);
    const int P = (int)(in_sizes[2] / ((long long)D * D));
    const size_t need = 32 + (size_t)P * (size_t)NT * sizeof(int);

    if (D == 256 && P == 8 && ws_size >= need) {
        int* counts  = (int*)d_ws;
        int* buckets = (int*)((char*)d_ws + 32);
        hipMemsetAsync(counts, 0, 32, stream);
        bucket_k<<<(NT + 255) / 256, 256, 0, stream>>>(xi, parts, counts, buckets, NT);
        dim3 grid(XB, 4, 8);
        fge_gemm<<<grid, 256, 0, stream>>>(xi, emb, wgt, counts, buckets, out, NT);
    } else {
        naive_k<<<NT, 256, 0, stream>>>(xi, emb, wgt, parts, out, D, P);
    }
}